// Round 11
// baseline (1070.205 us; speedup 1.0000x reference)
//
#include <hip/hip_runtime.h>

#define MDIM 8192   // B*S
#define KDIM 4096   // DIN
#define NDIM 11008  // DOUT

#define NBLK_W 1024
#define NBLK_X 2048

typedef float f32x4 __attribute__((ext_vector_type(4)));
typedef short bf16x8 __attribute__((ext_vector_type(8)));
typedef unsigned short us4 __attribute__((ext_vector_type(4)));
typedef unsigned short us8 __attribute__((ext_vector_type(8)));

#define GAS __attribute__((address_space(1)))
#define LAS __attribute__((address_space(3)))

__device__ __forceinline__ unsigned short f2bf(float f) {
  unsigned int u = __builtin_bit_cast(unsigned int, f);
  u += 0x7FFFu + ((u >> 16) & 1u);   // RTNE
  return (unsigned short)(u >> 16);
}

// --- Kernel 1: sign(W) -> +-1.0 bf16, fused with |W| partial reduction ---
__global__ __launch_bounds__(256) void k_convert_w(const float* __restrict__ w,
                                                   unsigned short* __restrict__ wq,
                                                   float* __restrict__ partials) {
  const int n4 = (NDIM * KDIM) / 4;
  const int stride = gridDim.x * blockDim.x;
  float s = 0.f;
  for (int i = blockIdx.x * blockDim.x + threadIdx.x; i < n4; i += stride) {
    f32x4 v = ((const f32x4*)w)[i];
    s += fabsf(v.x) + fabsf(v.y) + fabsf(v.z) + fabsf(v.w);
    us4 q;
    q.x = v.x > 0.f ? 0x3F80u : (v.x < 0.f ? 0xBF80u : 0u);
    q.y = v.y > 0.f ? 0x3F80u : (v.y < 0.f ? 0xBF80u : 0u);
    q.z = v.z > 0.f ? 0x3F80u : (v.z < 0.f ? 0xBF80u : 0u);
    q.w = v.w > 0.f ? 0x3F80u : (v.w < 0.f ? 0xBF80u : 0u);
    ((us4*)wq)[i] = q;
  }
  #pragma unroll
  for (int off = 32; off > 0; off >>= 1) s += __shfl_down(s, off, 64);
  __shared__ float red[4];
  if ((threadIdx.x & 63) == 0) red[threadIdx.x >> 6] = s;
  __syncthreads();
  if (threadIdx.x == 0) partials[blockIdx.x] = red[0] + red[1] + red[2] + red[3];
}

// --- Kernel 2: deterministic final reduction -> scale ---
__global__ __launch_bounds__(256) void k_scale(const float* __restrict__ partials,
                                               float* __restrict__ scale) {
  float s = 0.f;
  for (int i = threadIdx.x; i < NBLK_W; i += 256) s += partials[i];
  #pragma unroll
  for (int off = 32; off > 0; off >>= 1) s += __shfl_down(s, off, 64);
  __shared__ float red[4];
  if ((threadIdx.x & 63) == 0) red[threadIdx.x >> 6] = s;
  __syncthreads();
  if (threadIdx.x == 0)
    *scale = (red[0] + red[1] + red[2] + red[3]) / (float)((size_t)NDIM * KDIM);
}

// --- Kernel 3: x fp32 -> bf16 ---
__global__ __launch_bounds__(256) void k_convert_x(const float* __restrict__ x,
                                                   unsigned short* __restrict__ xb) {
  const int n8 = (MDIM * KDIM) / 8;
  const int stride = gridDim.x * blockDim.x;
  for (int i = blockIdx.x * blockDim.x + threadIdx.x; i < n8; i += stride) {
    f32x4 v0 = ((const f32x4*)x)[2 * i];
    f32x4 v1 = ((const f32x4*)x)[2 * i + 1];
    us8 q;
    q[0] = f2bf(v0.x); q[1] = f2bf(v0.y); q[2] = f2bf(v0.z); q[3] = f2bf(v0.w);
    q[4] = f2bf(v1.x); q[5] = f2bf(v1.y); q[6] = f2bf(v1.z); q[7] = f2bf(v1.w);
    ((us8*)xb)[i] = q;
  }
}

// --- Kernel 4: 256x256 8-phase bf16 MFMA GEMM (16x16x32), reads at phase-TOP ---
// C[m][n] = scale * sum_k A[m][k]*Bq[n][k] + bias[n]
// 8 waves (2M x 4N), per-wave 128x64, BK=64, 2 K-tiles/iter, 8 phases/iter.
// r10 post-mortem: 32x32 shape reverted (bank conflicts 6.8e7). r4-r9 all stall
// at ~48% because waves issue IN-ORDER: reads placed after the MFMA cluster
// can't issue until the cluster has issued (shared-pipe contention ~620cyc),
// so LDS idles under MFMA and vice versa -> serial 1141cyc phases.
// FIX: all frag reads issue at phase-TOP (before MFMA), consumed >=1 phase
// later. Enabled by A-frag ping-pong (afA=Alow, afB=Ahigh are separate arrays;
// frags 96 VGPR, r5-precedent fits the 128-VGPR cap alongside 128 AGPR acc).
// Quadrant order per buffer: g:(afA,bq01)(afA,bq23)(afB,bq01)(afB,bq23).
// Read map (phase-top): g0: bq23(b0)[4]+afB(b0)[8]   (used g1 / g2)
//                       g3: VM(2); afA(b1)[8]+bq01(b1)[4] (used g4 / g4,g6)
//                       g4: bq23(b1)[4]+afB(b1)[8]   (used g5 / g6)
//                       g7: VM(2); afA(b0')[8]+bq01(b0')[4] (used g0' / g0',g2')
// All reloads target regs whose last use is >=1 phase earlier (WAR-clean):
//   afA used g0,g1|g4,g5; afB g2,g3|g6,g7; bq01 g0,g2|g4,g6; bq23 g1,g3|g5,g7.
// Stage slots (unchanged r9): g0/g1 buf1.A<-K(2i+1); g2/g3 buf0.B<-K(2i+2);
//   g4/g5 buf0.A<-K(2i+2); g6/g7 buf1.B<-K(2i+3), at phase END.
// VM ledger: g3-top outstanding = prev-g6,g7(buf1.B) + g0,g1(buf1.A) + g2 = 10
//   -> VM(2) retires 8 = ALL of buf1 before its reads. g7-top: g2..g6 = 10 ->
//   VM(2) retires g2..g5 = all of buf0. Never 0 in-loop. Iter-0 identical via
//   prologue (buf0 8 loads retired by VM(4), buf1.B 4 in flight).
// Region WAR: every stage >=1 barrier after its readers' consuming-phase bar
//   (buf1.A@g0: free prev-g6; buf0.B@g2: free g1; buf0.A@g4: free g2;
//    buf1.B@g6: free g5). lgkm = ds_reads only (in-order) -> counted waits OK.
// SWIZZLE: 3-bit XOR in 64-short row (16x16 pattern, bank-conflict 0 verified).

#define BAR()  __builtin_amdgcn_s_barrier()
#define SB0()  __builtin_amdgcn_sched_barrier(0)
#define PRIO1() __builtin_amdgcn_s_setprio(1)
#define PRIO0() __builtin_amdgcn_s_setprio(0)
#define VM(N)  asm volatile("s_waitcnt vmcnt(" #N ")" ::: "memory")

#define STAGE(GP, ROWB, LDSOFF, HALF, KT) do {                                        \
  const unsigned short* _s = (GP) + (size_t)((ROWB) + (HALF)*128 + srow) * KDIM       \
                              + (KT)*64 + scol;                                       \
  unsigned short* _d = lds + (LDSOFF) + (HALF)*8192 + tid*8;                          \
  __builtin_amdgcn_global_load_lds((const GAS unsigned int*)_s,                       \
                                   (LAS unsigned int*)_d, 16, 0, 0);                  \
  __builtin_amdgcn_global_load_lds((const GAS unsigned int*)(_s + (size_t)64*KDIM),   \
                                   (LAS unsigned int*)(_d + 4096), 16, 0, 0);         \
} while (0)

// B col-group pair: DST[ni][kk] for output cols wn*64 + (NB+ni)*16 + l15
#define LOAD_B2(DST, BUF, NB)                                                         \
  _Pragma("unroll") for (int ni = 0; ni < 2; ++ni)                                    \
  _Pragma("unroll") for (int kk = 0; kk < 2; ++kk)                                    \
    DST[ni][kk] = *(const bf16x8*)&lds[(BUF)*32768 + 16384 + bWOff + ((NB)+ni)*1024   \
                                       + rowoff + rcol[kk]];

// A quarter (64 rows) of this wave's half: MQ=0 rows 0..63, MQ=1 rows 64..127
#define LOAD_A(DST, BUF, MQ)                                                          \
  _Pragma("unroll") for (int mi = 0; mi < 4; ++mi)                                    \
  _Pragma("unroll") for (int kk = 0; kk < 2; ++kk)                                    \
    DST[mi][kk] = *(const bf16x8*)&lds[(BUF)*32768 + aWOff + (MQ)*4096 + mi*1024      \
                                       + rowoff + rcol[kk]];

// 16 MFMA: 4 mi x 2 ni x 2 kk -> acc[MB+mi][NB+ni]
#define MFMA16(AF, MB, BQ, NB)                                                        \
  _Pragma("unroll") for (int kk = 0; kk < 2; ++kk)                                    \
  _Pragma("unroll") for (int mi = 0; mi < 4; ++mi)                                    \
  _Pragma("unroll") for (int ni = 0; ni < 2; ++ni)                                    \
    acc[(MB)+mi][(NB)+ni] = __builtin_amdgcn_mfma_f32_16x16x32_bf16(                  \
        AF[mi][kk], BQ[ni][kk], acc[(MB)+mi][(NB)+ni], 0, 0, 0);

__global__ __launch_bounds__(512, 2) void k_gemm256(const unsigned short* __restrict__ A,
                                                    const unsigned short* __restrict__ B,
                                                    const float* __restrict__ bias,
                                                    const float* __restrict__ scale_p,
                                                    float* __restrict__ C) {
  extern __shared__ unsigned short lds[];

  const int nTn = NDIM / 256;                  // 43
  const int nwg = (MDIM / 256) * nTn;          // 1376 (== 0 mod 8)
  int wg = (int)blockIdx.x;
  wg = (wg & 7) * (nwg / 8) + (wg >> 3);       // XCD-aware swizzle (bijective)
  const int tm = wg / nTn;
  const int tn = wg % nTn;

  const int tid  = (int)threadIdx.x;
  const int lane = tid & 63;
  const int wave = tid >> 6;                   // 0..7
  const int wm   = wave >> 2;                  // 0..1  (M)
  const int wn   = wave & 3;                   // 0..3  (N)
  const int l15  = lane & 15;

  // read-side: row = l15 (+16-multiples), col = (hi*8 + kk*32) ^ ((l15&7)<<3)
  const int rowoff = l15 * 64;
  const int rsw = (l15 & 7) << 3;
  int rcol[2];
  rcol[0] = ((lane >> 4) * 8) ^ rsw;
  rcol[1] = ((lane >> 4) * 8 + 32) ^ rsw;
  // stage-side: LDS linear dest; pre-swizzled GLOBAL source column (rule #21)
  const int scol = ((tid & 7) * 8) ^ (((tid >> 3) & 7) << 3);
  const int srow = tid >> 3;                   // 0..63

  const int aWOff = wm * 8192;                             // this wave's A half
  const int bWOff = (wn >> 1) * 8192 + (wn & 1) * 4096;    // this wave's 64-row B chunk
  const int aRow = tm * 256;
  const int bRow = tn * 256;

  f32x4 acc[8][4];
  #pragma unroll
  for (int i = 0; i < 8; ++i)
    #pragma unroll
    for (int j = 0; j < 4; ++j) acc[i][j] = f32x4{0.f, 0.f, 0.f, 0.f};

  bf16x8 afA[4][2], afB[4][2], bq01[2][2], bq23[2][2];

  // ---- prologue: K0 -> buf0 (B,A); K1.B -> buf1; pre-read g0's operands ----
  STAGE(B, bRow, 16384, 0, 0);
  STAGE(B, bRow, 16384, 1, 0);
  STAGE(A, aRow, 0,     0, 0);
  STAGE(A, aRow, 0,     1, 0);
  STAGE(B, bRow, 49152, 0, 1);
  STAGE(B, bRow, 49152, 1, 1);
  VM(4);                                        // buf0 K0 fully landed
  SB0();
  BAR();
  LOAD_A(afA, 0, 0); LOAD_B2(bq01, 0, 0);       // g0's MFMA operands

  #pragma unroll 1
  for (int i = 0; i < 32; ++i) {
    const int kA = 2 * i + 1;                            // <= 63
    const int kB = (2 * i + 2 > 63) ? 63 : 2 * i + 2;    // clamped tail
    const int kC = (2 * i + 3 > 63) ? 63 : 2 * i + 3;
    // g0: reads bq23(b0)+afB(b0) at TOP; MFMA(afA,bq01)@L01; stage buf1.A.h0<-kA
    LOAD_B2(bq23, 0, 2); LOAD_A(afB, 0, 1); SB0();
    PRIO1(); MFMA16(afA, 0, bq01, 0); PRIO0(); SB0();
    STAGE(A, aRow, 32768, 0, kA);
    BAR();
    // g1: MFMA(afA,bq23)@L23; stage buf1.A.h1
    PRIO1(); MFMA16(afA, 0, bq23, 2); PRIO0(); SB0();
    STAGE(A, aRow, 32768, 1, kA);
    BAR();
    // g2: MFMA(afB,bq01)@H01; stage buf0.B.h0<-kB
    PRIO1(); MFMA16(afB, 4, bq01, 0); PRIO0(); SB0();
    STAGE(B, bRow, 16384, 0, kB);
    BAR();
    // g3: VM(2) lands buf1; reads afA(b1)+bq01(b1) at TOP; MFMA(afB,bq23)@H23;
    //     stage buf0.B.h1
    VM(2);
    LOAD_A(afA, 1, 0); LOAD_B2(bq01, 1, 0); SB0();
    PRIO1(); MFMA16(afB, 4, bq23, 2); PRIO0(); SB0();
    STAGE(B, bRow, 16384, 1, kB);
    BAR();
    // g4: reads bq23(b1)+afB(b1) at TOP; MFMA(afA,bq01)@L01(b1); stage buf0.A.h0<-kB
    LOAD_B2(bq23, 1, 2); LOAD_A(afB, 1, 1); SB0();
    PRIO1(); MFMA16(afA, 0, bq01, 0); PRIO0(); SB0();
    STAGE(A, aRow, 0, 0, kB);
    BAR();
    // g5: MFMA(afA,bq23); stage buf0.A.h1
    PRIO1(); MFMA16(afA, 0, bq23, 2); PRIO0(); SB0();
    STAGE(A, aRow, 0, 1, kB);
    BAR();
    // g6: MFMA(afB,bq01); stage buf1.B.h0<-kC
    PRIO1(); MFMA16(afB, 4, bq01, 0); PRIO0(); SB0();
    STAGE(B, bRow, 49152, 0, kC);
    BAR();
    // g7: VM(2) lands buf0(kB); reads afA(b0')+bq01(b0') at TOP; MFMA(afB,bq23);
    //     stage buf1.B.h1
    VM(2);
    LOAD_A(afA, 0, 0); LOAD_B2(bq01, 0, 0); SB0();
    PRIO1(); MFMA16(afB, 4, bq23, 2); PRIO0(); SB0();
    STAGE(B, bRow, 49152, 1, kC);
    BAR();
  }

  VM(0);  // drain tail prefetch stages before epilogue

  const float sc = *scale_p;
  float bv[4];
  #pragma unroll
  for (int ni = 0; ni < 4; ++ni) bv[ni] = bias[tn * 256 + wn * 64 + ni * 16 + l15];

  // C/D layout: col = lane&15, row = (lane>>4)*4 + reg
  #pragma unroll
  for (int mi = 0; mi < 8; ++mi) {
    #pragma unroll
    for (int r = 0; r < 4; ++r) {
      const int m = tm * 256 + wm * 128 + mi * 16 + (lane >> 4) * 4 + r;
      float* crow = C + (size_t)m * NDIM + tn * 256 + wn * 64;
      #pragma unroll
      for (int ni = 0; ni < 4; ++ni)
        crow[ni * 16 + l15] = sc * acc[mi][ni][r] + bv[ni];
    }
  }
}

extern "C" void kernel_launch(void* const* d_in, const int* in_sizes, int n_in,
                              void* d_out, int out_size, void* d_ws, size_t ws_size,
                              hipStream_t stream) {
  const float* x = (const float*)d_in[0];
  const float* w = (const float*)d_in[1];
  const float* bias = (const float*)d_in[2];
  float* out = (float*)d_out;

  char* ws = (char*)d_ws;
  const size_t XB_BYTES = (size_t)MDIM * KDIM * 2;
  const size_t WQ_BYTES = (size_t)NDIM * KDIM * 2;
  unsigned short* xb = (unsigned short*)ws;
  unsigned short* wq = (unsigned short*)(ws + XB_BYTES);
  float* partials = (float*)(ws + XB_BYTES + WQ_BYTES);
  float* scale = partials + NBLK_W;

  k_convert_w<<<NBLK_W, 256, 0, stream>>>(w, wq, partials);
  k_scale<<<1, 256, 0, stream>>>(partials, scale);
  k_convert_x<<<NBLK_X, 256, 0, stream>>>(x, xb);

  (void)hipFuncSetAttribute((const void*)k_gemm256,
                            hipFuncAttributeMaxDynamicSharedMemorySize, 131072);
  const int grid = (MDIM / 256) * (NDIM / 256);  // 1376
  k_gemm256<<<grid, 512, 131072, stream>>>(xb, wq, bias, scale, out);
}

// Round 12
// 712.959 us; speedup vs baseline: 1.5011x; 1.5011x over previous
//
#include <hip/hip_runtime.h>

#define MDIM 8192   // B*S
#define KDIM 4096   // DIN
#define NDIM 11008  // DOUT

#define NBLK_W 1024
#define NBLK_X 2048

typedef float f32x4 __attribute__((ext_vector_type(4)));
typedef short bf16x8 __attribute__((ext_vector_type(8)));
typedef unsigned short us4 __attribute__((ext_vector_type(4)));
typedef unsigned short us8 __attribute__((ext_vector_type(8)));

#define GAS __attribute__((address_space(1)))
#define LAS __attribute__((address_space(3)))

__device__ __forceinline__ unsigned short f2bf(float f) {
  unsigned int u = __builtin_bit_cast(unsigned int, f);
  u += 0x7FFFu + ((u >> 16) & 1u);   // RTNE
  return (unsigned short)(u >> 16);
}

// --- Kernel 1: sign(W) -> +-1.0 bf16, fused with |W| partial reduction ---
__global__ __launch_bounds__(256) void k_convert_w(const float* __restrict__ w,
                                                   unsigned short* __restrict__ wq,
                                                   float* __restrict__ partials) {
  const int n4 = (NDIM * KDIM) / 4;
  const int stride = gridDim.x * blockDim.x;
  float s = 0.f;
  for (int i = blockIdx.x * blockDim.x + threadIdx.x; i < n4; i += stride) {
    f32x4 v = ((const f32x4*)w)[i];
    s += fabsf(v.x) + fabsf(v.y) + fabsf(v.z) + fabsf(v.w);
    us4 q;
    q.x = v.x > 0.f ? 0x3F80u : (v.x < 0.f ? 0xBF80u : 0u);
    q.y = v.y > 0.f ? 0x3F80u : (v.y < 0.f ? 0xBF80u : 0u);
    q.z = v.z > 0.f ? 0x3F80u : (v.z < 0.f ? 0xBF80u : 0u);
    q.w = v.w > 0.f ? 0x3F80u : (v.w < 0.f ? 0xBF80u : 0u);
    ((us4*)wq)[i] = q;
  }
  #pragma unroll
  for (int off = 32; off > 0; off >>= 1) s += __shfl_down(s, off, 64);
  __shared__ float red[4];
  if ((threadIdx.x & 63) == 0) red[threadIdx.x >> 6] = s;
  __syncthreads();
  if (threadIdx.x == 0) partials[blockIdx.x] = red[0] + red[1] + red[2] + red[3];
}

// --- Kernel 2: deterministic final reduction -> scale ---
__global__ __launch_bounds__(256) void k_scale(const float* __restrict__ partials,
                                               float* __restrict__ scale) {
  float s = 0.f;
  for (int i = threadIdx.x; i < NBLK_W; i += 256) s += partials[i];
  #pragma unroll
  for (int off = 32; off > 0; off >>= 1) s += __shfl_down(s, off, 64);
  __shared__ float red[4];
  if ((threadIdx.x & 63) == 0) red[threadIdx.x >> 6] = s;
  __syncthreads();
  if (threadIdx.x == 0)
    *scale = (red[0] + red[1] + red[2] + red[3]) / (float)((size_t)NDIM * KDIM);
}

// --- Kernel 3: x fp32 -> bf16 ---
__global__ __launch_bounds__(256) void k_convert_x(const float* __restrict__ x,
                                                   unsigned short* __restrict__ xb) {
  const int n8 = (MDIM * KDIM) / 8;
  const int stride = gridDim.x * blockDim.x;
  for (int i = blockIdx.x * blockDim.x + threadIdx.x; i < n8; i += stride) {
    f32x4 v0 = ((const f32x4*)x)[2 * i];
    f32x4 v1 = ((const f32x4*)x)[2 * i + 1];
    us8 q;
    q[0] = f2bf(v0.x); q[1] = f2bf(v0.y); q[2] = f2bf(v0.z); q[3] = f2bf(v0.w);
    q[4] = f2bf(v1.x); q[5] = f2bf(v1.y); q[6] = f2bf(v1.z); q[7] = f2bf(v1.w);
    ((us8*)xb)[i] = q;
  }
}

// --- Kernel 4: 256x256 8-phase bf16 MFMA GEMM, m201-depth vmcnt ledger ---
// C[m][n] = scale * sum_k A[m][k]*Bq[n][k] + bias[n]
// 8 waves (2M x 4N), per-wave 128x64, BK=64, 2 K-tiles/iter, 8 phases/iter.
// r4's proven two-barrier phase shape; CHANGE = m201's deep prefetch ledger:
//   1 half-tile staged per phase, VM(6) ONLY at g3/g7, so drained loads are
//   3-6 phases (3400-6800 cyc) old -- vs r4-r9's VM(2/4) draining 1-2-phase-old
//   loads (~HBM latency, stalls every g3/g7; the measured ~2100 cyc/K-tile gap).
// Reads front-loaded so regions free early: g0: bq23,bq01,afL (16); g2: afH (8);
//   g1,g3: none. Same for buf1 at g4/g6. Frags bq01+bq23+af = 64 VGPR (r4 budget,
//   no spill; r11's 96-frag ping-pong spilled and is abandoned).
// Stage slots (iter i): g0: K(2i+1).A1->buf1.A.h1; g1: K(2i+2).B0->buf0.B.h0;
//   g2: K(2i+2).B1; g3: K(2i+2).A0 +VM(6); g4: K(2i+2).A1; g5: K(2i+3).B0->buf1;
//   g6: K(2i+3).B1; g7: K(2i+3).A0 +VM(6).
// Ledger (steady state, verified): after each VM(6) exactly 3 stage-ops (6 loads)
//   remain = {B0,B1,A0} of the NEXT K-tile pair member. At g3: retires
//   K(2i+1).{B0,B1,A0,A1} (ages 6,5,4,3 phases) -> buf1 complete before g4 reads.
//   At g7: retires K(2i+2).{B0,B1,A0,A1} -> buf0 complete before next g0. Never
//   drains below 6 in-loop. Prologue: 7 stages + VM(6) reproduces the invariant.
// WAR (stage vs region readers, all >=1 phase + ~900cyc land time after the
//   region's reads completed via the consuming MFMA's lgkm): buf0.B@g1/g2 (read
//   g0); buf0.A.h0@g3 (read g0); buf0.A.h1@g4 (read g2); buf1.B@g5/g6 (read g4);
//   buf1.A.h0@g7 (read g4); buf1.A.h1@g0 (read prev g6).
// Tail: kB/kC clamp to 63 -> re-stages identical K63 data (idempotent; keeps the
//   vmcnt ledger exact). No other loop VMEM.
// SWIZZLE: 3-bit XOR in 64-short row (kk folded inside); bank-conflict 0
//   (verified r4/r7/r9).

#define BAR()  __builtin_amdgcn_s_barrier()
#define SB0()  __builtin_amdgcn_sched_barrier(0)
#define PRIO1() __builtin_amdgcn_s_setprio(1)
#define PRIO0() __builtin_amdgcn_s_setprio(0)
#define VM(N)  asm volatile("s_waitcnt vmcnt(" #N ")" ::: "memory")

#define STAGE(GP, ROWB, LDSOFF, HALF, KT) do {                                        \
  const unsigned short* _s = (GP) + (size_t)((ROWB) + (HALF)*128 + srow) * KDIM       \
                              + (KT)*64 + scol;                                       \
  unsigned short* _d = lds + (LDSOFF) + (HALF)*8192 + tid*8;                          \
  __builtin_amdgcn_global_load_lds((const GAS unsigned int*)_s,                       \
                                   (LAS unsigned int*)_d, 16, 0, 0);                  \
  __builtin_amdgcn_global_load_lds((const GAS unsigned int*)(_s + (size_t)64*KDIM),   \
                                   (LAS unsigned int*)(_d + 4096), 16, 0, 0);         \
} while (0)

// B col-group pair: DST[ni][kk] for output cols wn*64 + (NB+ni)*16 + l15
#define LOAD_B2(DST, BUF, NB)                                                         \
  _Pragma("unroll") for (int ni = 0; ni < 2; ++ni)                                    \
  _Pragma("unroll") for (int kk = 0; kk < 2; ++kk)                                    \
    DST[ni][kk] = *(const bf16x8*)&lds[(BUF)*32768 + 16384 + bWOff + ((NB)+ni)*1024   \
                                       + rowoff + rcol[kk]];

// A quarter (64 rows) of this wave's half: MQ=0 rows 0..63, MQ=1 rows 64..127
#define LOAD_A(DST, BUF, MQ)                                                          \
  _Pragma("unroll") for (int mi = 0; mi < 4; ++mi)                                    \
  _Pragma("unroll") for (int kk = 0; kk < 2; ++kk)                                    \
    DST[mi][kk] = *(const bf16x8*)&lds[(BUF)*32768 + aWOff + (MQ)*4096 + mi*1024      \
                                       + rowoff + rcol[kk]];

// 16 MFMA: 4 mi x 2 ni x 2 kk -> acc[MB+mi][NB+ni]
#define MFMA16(AF, MB, BQ, NB)                                                        \
  _Pragma("unroll") for (int kk = 0; kk < 2; ++kk)                                    \
  _Pragma("unroll") for (int mi = 0; mi < 4; ++mi)                                    \
  _Pragma("unroll") for (int ni = 0; ni < 2; ++ni)                                    \
    acc[(MB)+mi][(NB)+ni] = __builtin_amdgcn_mfma_f32_16x16x32_bf16(                  \
        AF[mi][kk], BQ[ni][kk], acc[(MB)+mi][(NB)+ni], 0, 0, 0);

__global__ __launch_bounds__(512, 2) void k_gemm256(const unsigned short* __restrict__ A,
                                                    const unsigned short* __restrict__ B,
                                                    const float* __restrict__ bias,
                                                    const float* __restrict__ scale_p,
                                                    float* __restrict__ C) {
  extern __shared__ unsigned short lds[];

  const int nTn = NDIM / 256;                  // 43
  const int nwg = (MDIM / 256) * nTn;          // 1376 (== 0 mod 8)
  int wg = (int)blockIdx.x;
  wg = (wg & 7) * (nwg / 8) + (wg >> 3);       // XCD-aware swizzle (bijective)
  const int tm = wg / nTn;
  const int tn = wg % nTn;

  const int tid  = (int)threadIdx.x;
  const int lane = tid & 63;
  const int wave = tid >> 6;                   // 0..7
  const int wm   = wave >> 2;                  // 0..1  (M)
  const int wn   = wave & 3;                   // 0..3  (N)
  const int l15  = lane & 15;

  // read-side: row = l15 (+16-multiples), col = (hi*8 + kk*32) ^ ((l15&7)<<3)
  const int rowoff = l15 * 64;
  const int rsw = (l15 & 7) << 3;
  int rcol[2];
  rcol[0] = ((lane >> 4) * 8) ^ rsw;
  rcol[1] = ((lane >> 4) * 8 + 32) ^ rsw;
  // stage-side: LDS linear dest; pre-swizzled GLOBAL source column (rule #21)
  const int scol = ((tid & 7) * 8) ^ (((tid >> 3) & 7) << 3);
  const int srow = tid >> 3;                   // 0..63

  const int aWOff = wm * 8192;                             // this wave's A half
  const int bWOff = (wn >> 1) * 8192 + (wn & 1) * 4096;    // this wave's 64-row B chunk
  const int aRow = tm * 256;
  const int bRow = tn * 256;

  f32x4 acc[8][4];
  #pragma unroll
  for (int i = 0; i < 8; ++i)
    #pragma unroll
    for (int j = 0; j < 4; ++j) acc[i][j] = f32x4{0.f, 0.f, 0.f, 0.f};

  bf16x8 af[4][2], bq01[2][2], bq23[2][2];

  // ---- prologue: K0 full -> buf0; K1.{B0,B1,A0} -> buf1; VM(6) ----
  STAGE(B, bRow, 16384, 0, 0);
  STAGE(B, bRow, 16384, 1, 0);
  STAGE(A, aRow, 0,     0, 0);
  STAGE(A, aRow, 0,     1, 0);
  STAGE(B, bRow, 49152, 0, 1);
  STAGE(B, bRow, 49152, 1, 1);
  STAGE(A, aRow, 32768, 0, 1);
  VM(6);                                        // retires K0 (8 loads); K1 6 in flight
  SB0();
  BAR();

  #pragma unroll 1
  for (int i = 0; i < 32; ++i) {
    const int kA = 2 * i + 1;                            // <= 63 always
    const int kB = (2 * i + 2 > 63) ? 63 : 2 * i + 2;    // clamped tail
    const int kC = (2 * i + 3 > 63) ? 63 : 2 * i + 3;
    // g0: reads bq23,bq01,afL (buf0); stage buf1.A.h1 <- kA; MFMA(afL,bq01)
    LOAD_B2(bq23, 0, 2); LOAD_B2(bq01, 0, 0); LOAD_A(af, 0, 0);
    STAGE(A, aRow, 32768, 1, kA);
    BAR();
    PRIO1(); MFMA16(af, 0, bq01, 0); PRIO0(); SB0(); BAR();
    // g1: no reads; stage buf0.B.h0 <- kB; MFMA(afL,bq23)
    STAGE(B, bRow, 16384, 0, kB);
    BAR();
    PRIO1(); MFMA16(af, 0, bq23, 2); PRIO0(); SB0(); BAR();
    // g2: reads afH (buf0); stage buf0.B.h1 <- kB; MFMA(afH,bq01)
    LOAD_A(af, 0, 1);
    STAGE(B, bRow, 16384, 1, kB);
    BAR();
    PRIO1(); MFMA16(af, 4, bq01, 0); PRIO0(); SB0(); BAR();
    // g3: stage buf0.A.h0 <- kB; MFMA(afH,bq23); VM(6) -> buf1 complete
    STAGE(A, aRow, 0, 0, kB);
    BAR();
    PRIO1(); MFMA16(af, 4, bq23, 2); PRIO0();
    VM(6); SB0(); BAR();
    // g4: reads bq23,bq01,afL (buf1); stage buf0.A.h1 <- kB; MFMA(afL,bq01)
    LOAD_B2(bq23, 1, 2); LOAD_B2(bq01, 1, 0); LOAD_A(af, 1, 0);
    STAGE(A, aRow, 0, 1, kB);
    BAR();
    PRIO1(); MFMA16(af, 0, bq01, 0); PRIO0(); SB0(); BAR();
    // g5: no reads; stage buf1.B.h0 <- kC; MFMA(afL,bq23)
    STAGE(B, bRow, 49152, 0, kC);
    BAR();
    PRIO1(); MFMA16(af, 0, bq23, 2); PRIO0(); SB0(); BAR();
    // g6: reads afH (buf1); stage buf1.B.h1 <- kC; MFMA(afH,bq01)
    LOAD_A(af, 1, 1);
    STAGE(B, bRow, 49152, 1, kC);
    BAR();
    PRIO1(); MFMA16(af, 4, bq01, 0); PRIO0(); SB0(); BAR();
    // g7: stage buf1.A.h0 <- kC; MFMA(afH,bq23); VM(6) -> buf0 complete
    STAGE(A, aRow, 32768, 0, kC);
    BAR();
    PRIO1(); MFMA16(af, 4, bq23, 2); PRIO0();
    VM(6); SB0(); BAR();
  }

  VM(0);  // drain the 6 tail prefetches before epilogue

  const float sc = *scale_p;
  float bv[4];
  #pragma unroll
  for (int ni = 0; ni < 4; ++ni) bv[ni] = bias[tn * 256 + wn * 64 + ni * 16 + l15];

  // C/D layout: col = lane&15, row = (lane>>4)*4 + reg
  #pragma unroll
  for (int mi = 0; mi < 8; ++mi) {
    #pragma unroll
    for (int r = 0; r < 4; ++r) {
      const int m = tm * 256 + wm * 128 + mi * 16 + (lane >> 4) * 4 + r;
      float* crow = C + (size_t)m * NDIM + tn * 256 + wn * 64;
      #pragma unroll
      for (int ni = 0; ni < 4; ++ni)
        crow[ni * 16 + l15] = sc * acc[mi][ni][r] + bv[ni];
    }
  }
}

extern "C" void kernel_launch(void* const* d_in, const int* in_sizes, int n_in,
                              void* d_out, int out_size, void* d_ws, size_t ws_size,
                              hipStream_t stream) {
  const float* x = (const float*)d_in[0];
  const float* w = (const float*)d_in[1];
  const float* bias = (const float*)d_in[2];
  float* out = (float*)d_out;

  char* ws = (char*)d_ws;
  const size_t XB_BYTES = (size_t)MDIM * KDIM * 2;
  const size_t WQ_BYTES = (size_t)NDIM * KDIM * 2;
  unsigned short* xb = (unsigned short*)ws;
  unsigned short* wq = (unsigned short*)(ws + XB_BYTES);
  float* partials = (float*)(ws + XB_BYTES + WQ_BYTES);
  float* scale = partials + NBLK_W;

  k_convert_w<<<NBLK_W, 256, 0, stream>>>(w, wq, partials);
  k_scale<<<1, 256, 0, stream>>>(partials, scale);
  k_convert_x<<<NBLK_X, 256, 0, stream>>>(x, xb);

  (void)hipFuncSetAttribute((const void*)k_gemm256,
                            hipFuncAttributeMaxDynamicSharedMemorySize, 131072);
  const int grid = (MDIM / 256) * (NDIM / 256);  // 1376
  k_gemm256<<<grid, 512, 131072, stream>>>(xb, wq, bias, scale, out);
}

// Round 13
// 506.674 us; speedup vs baseline: 2.1122x; 1.4071x over previous
//
#include <hip/hip_runtime.h>

#define MDIM 8192   // B*S
#define KDIM 4096   // DIN
#define NDIM 11008  // DOUT

#define NBLK_W 1024

typedef float f32x4 __attribute__((ext_vector_type(4)));
typedef int   i32x4 __attribute__((ext_vector_type(4)));
typedef char  c4    __attribute__((ext_vector_type(4)));

#define GAS __attribute__((address_space(1)))
#define LAS __attribute__((address_space(3)))

// --- Kernel 1: sign(W) -> {-1,0,+1} i8, fused with |W| partial reduction ---
__global__ __launch_bounds__(256) void k_convert_w(const float* __restrict__ w,
                                                   char* __restrict__ wq,
                                                   float* __restrict__ partials) {
  const int n4 = (NDIM * KDIM) / 4;
  const int stride = gridDim.x * blockDim.x;
  float s = 0.f;
  for (int i = blockIdx.x * blockDim.x + threadIdx.x; i < n4; i += stride) {
    f32x4 v = ((const f32x4*)w)[i];
    s += fabsf(v.x) + fabsf(v.y) + fabsf(v.z) + fabsf(v.w);
    c4 q;
    q.x = v.x > 0.f ? 1 : (v.x < 0.f ? -1 : 0);
    q.y = v.y > 0.f ? 1 : (v.y < 0.f ? -1 : 0);
    q.z = v.z > 0.f ? 1 : (v.z < 0.f ? -1 : 0);
    q.w = v.w > 0.f ? 1 : (v.w < 0.f ? -1 : 0);
    ((c4*)wq)[i] = q;
  }
  #pragma unroll
  for (int off = 32; off > 0; off >>= 1) s += __shfl_down(s, off, 64);
  __shared__ float red[4];
  if ((threadIdx.x & 63) == 0) red[threadIdx.x >> 6] = s;
  __syncthreads();
  if (threadIdx.x == 0) partials[blockIdx.x] = red[0] + red[1] + red[2] + red[3];
}

// --- Kernel 2: deterministic final reduction -> scale_w = mean|W| ---
__global__ __launch_bounds__(256) void k_scale(const float* __restrict__ partials,
                                               float* __restrict__ scale) {
  float s = 0.f;
  for (int i = threadIdx.x; i < NBLK_W; i += 256) s += partials[i];
  #pragma unroll
  for (int off = 32; off > 0; off >>= 1) s += __shfl_down(s, off, 64);
  __shared__ float red[4];
  if ((threadIdx.x & 63) == 0) red[threadIdx.x >> 6] = s;
  __syncthreads();
  if (threadIdx.x == 0)
    *scale = (red[0] + red[1] + red[2] + red[3]) / (float)((size_t)NDIM * KDIM);
}

// --- Kernel 3: x fp32 -> i8 with per-row scale s_x[m] = max|x[m,:]|/127 ---
// One block per row (4096 elems, 256 threads x 16). Exact row max -> no clip.
__global__ __launch_bounds__(256) void k_convert_x(const float* __restrict__ x,
                                                   char* __restrict__ xq,
                                                   float* __restrict__ sx) {
  const int row = blockIdx.x;
  const float* xr = x + (size_t)row * KDIM;
  const int t = (int)threadIdx.x;
  f32x4 v[4];
  float mx = 0.f;
  #pragma unroll
  for (int j = 0; j < 4; ++j) {
    v[j] = *(const f32x4*)(xr + j * 1024 + t * 4);
    mx = fmaxf(mx, fmaxf(fmaxf(fabsf(v[j].x), fabsf(v[j].y)),
                         fmaxf(fabsf(v[j].z), fabsf(v[j].w))));
  }
  #pragma unroll
  for (int off = 32; off > 0; off >>= 1) mx = fmaxf(mx, __shfl_xor(mx, off, 64));
  __shared__ float red[4];
  __shared__ float bmax;
  if ((t & 63) == 0) red[t >> 6] = mx;
  __syncthreads();
  if (t == 0) {
    float m2 = fmaxf(fmaxf(red[0], red[1]), fmaxf(red[2], red[3]));
    m2 = fmaxf(m2, 1e-20f);
    bmax = m2;
    sx[row] = m2 * (1.f / 127.f);
  }
  __syncthreads();
  const float r = 127.f / bmax;
  #pragma unroll
  for (int j = 0; j < 4; ++j) {
    int a = __float2int_rn(v[j].x * r), b = __float2int_rn(v[j].y * r);
    int c = __float2int_rn(v[j].z * r), d = __float2int_rn(v[j].w * r);
    a = a > 127 ? 127 : (a < -127 ? -127 : a);
    b = b > 127 ? 127 : (b < -127 ? -127 : b);
    c = c > 127 ? 127 : (c < -127 ? -127 : c);
    d = d > 127 ? 127 : (d < -127 ? -127 : d);
    c4 q; q.x = (char)a; q.y = (char)b; q.z = (char)c; q.w = (char)d;
    *(c4*)(xq + (size_t)row * KDIM + j * 1024 + t * 4) = q;
  }
}

// --- Kernel 4: 256x256 8-phase i8 MFMA GEMM (r9 skeleton, i32 exact accum) ---
// C[m][n] = scale_w * sx[m] * (sum_k xq[m][k]*wq[n][k]) + bias[n]
// 8 waves (2M x 4N), per-wave 128x64, BK=64 (= one 16x16x64 MFMA K), 2 K-tiles/
// iter, 8 phases/iter, MFMA-first single-barrier phases (r9, best 654us bf16).
// i8 halves MFMA pipe time, LDS frag bytes, stage bytes, HBM fetch vs bf16.
// LDS 64 KiB (bytes): buf0{A:0,B:16384} buf1{A:32768,B:49152}; half = 8192 B
//   = 128 rows x 64 B; staged by ONE global_load_lds x16B per thread.
// Frag layout (analogy of verified bf16 16x16x32): lane: row=l&15, k=(l>>4)*16
//   +[0..16) consecutive bytes -> one ds_read_b128 per frag. acc i32x4, C/D
//   layout dtype-independent (m121-128): col=lane&15, row=(lane>>4)*4+reg.
// Phase g: PRIO1; MFMA8(operands from g-1); PRIO0; SB0; [loads for g+1];
//          STAGE(1 half-tile); [VM(1) at g2/g6]; BAR
// Quadrant order per buffer: (L,01)(L,23)(H,01)(H,23); af[4] reused L/H.
// Load map: g0:bq23(b0) g1:afH(b0) g2:- g3:afL(b1)+bq01(b1) g4:bq23(b1)
//           g5:afH(b1) g6:- g7:afL(b0')+bq01(b0').
// Stage slots: g0/g1 buf1.A.h0/h1<-kA; g2/g3 buf0.B.h0/h1<-kB; g4/g5 buf0.A<-kB;
//              g6/g7 buf1.B<-kC. Ledger (1 load/stage): at g2-end outstanding =
//   prev{g6,g7}(2)+{g0,g1}(2)+g2(1)=5 -> VM(1) retires buf1's 4 before g3 reads;
//   at g6-end: g2..g6 = 5 -> VM(1) retires buf0's 4 before g7 reads. Never 0
//   in-loop. Prologue: 6 stages + VM(2) reproduces invariant. WAR: identical
//   lifetimes to r9 (verified there). No other loop VMEM (frags 32 VGPR).
// SWIZZLE (64 B rows): LDS(row, c) holds G(row, c ^ (((row>>1)&3)<<4));
//   read col = (hi<<4) ^ (((row&15)>>1 &3)<<4). Bank-quad = (4*row + hi^s) mod 8
//   -> uniform 8 lanes/quad = 2-way = free. Stage src col pre-swizzled (rule 21).

#define BAR()  __builtin_amdgcn_s_barrier()
#define SB0()  __builtin_amdgcn_sched_barrier(0)
#define PRIO1() __builtin_amdgcn_s_setprio(1)
#define PRIO0() __builtin_amdgcn_s_setprio(0)
#define VM(N)  asm volatile("s_waitcnt vmcnt(" #N ")" ::: "memory")

#define STAGE(GP, ROWB, LDSOFF, HALF, KT) do {                                        \
  const char* _s = (GP) + (size_t)((ROWB) + (HALF)*128 + srow) * KDIM                 \
                   + (KT)*64 + scol;                                                  \
  char* _d = lds + (LDSOFF) + (HALF)*8192 + tid*16;                                   \
  __builtin_amdgcn_global_load_lds((const GAS unsigned int*)_s,                       \
                                   (LAS unsigned int*)_d, 16, 0, 0);                  \
} while (0)

// B frag pair: DST[ni] covers output cols wn*64 + (NB+ni)*16 + (lane&15)
#define LOAD_B2(DST, BUF, NB)                                                         \
  _Pragma("unroll") for (int ni = 0; ni < 2; ++ni)                                    \
    DST[ni] = *(const i32x4*)&lds[(BUF)*32768 + 16384 + bWOff + ((NB)+ni)*1024        \
                                  + rowoff + rcol];

// A frags: 4 Mtiles of this wave's half; MQ=0 rows 0..63, MQ=1 rows 64..127
#define LOAD_A(DST, BUF, MQ)                                                          \
  _Pragma("unroll") for (int mi = 0; mi < 4; ++mi)                                    \
    DST[mi] = *(const i32x4*)&lds[(BUF)*32768 + aWOff + (MQ)*4096 + mi*1024           \
                                  + rowoff + rcol];

// 8 MFMA (16x16x64 i8): 4 mi x 2 ni -> acc[MB+mi][NB+ni]
#define MFMA8(AF, MB, BQ, NB)                                                         \
  _Pragma("unroll") for (int mi = 0; mi < 4; ++mi)                                    \
  _Pragma("unroll") for (int ni = 0; ni < 2; ++ni)                                    \
    acc[(MB)+mi][(NB)+ni] = __builtin_amdgcn_mfma_i32_16x16x64_i8(                    \
        AF[mi], BQ[ni], acc[(MB)+mi][(NB)+ni], 0, 0, 0);

__global__ __launch_bounds__(512, 2) void k_gemm256(const char* __restrict__ A,
                                                    const char* __restrict__ B,
                                                    const float* __restrict__ bias,
                                                    const float* __restrict__ sx,
                                                    const float* __restrict__ scale_p,
                                                    float* __restrict__ C) {
  extern __shared__ char lds[];

  const int nTn = NDIM / 256;                  // 43
  const int nwg = (MDIM / 256) * nTn;          // 1376 (== 0 mod 8)
  int wg = (int)blockIdx.x;
  wg = (wg & 7) * (nwg / 8) + (wg >> 3);       // XCD-aware swizzle (bijective)
  const int tm = wg / nTn;
  const int tn = wg % nTn;

  const int tid  = (int)threadIdx.x;
  const int lane = tid & 63;
  const int wave = tid >> 6;                   // 0..7
  const int wm   = wave >> 2;                  // 0..1  (M)
  const int wn   = wave & 3;                   // 0..3  (N)
  const int l15  = lane & 15;

  // read-side: row = l15 (+16-mults), byte col = (hi<<4) ^ (((l15>>1)&3)<<4)
  const int rowoff = l15 * 64;
  const int rcol = ((lane >> 4) << 4) ^ (((l15 >> 1) & 3) << 4);
  // stage-side: linear LDS dest; pre-swizzled GLOBAL source column (rule #21)
  const int srow = tid >> 2;                   // 0..127
  const int scol = ((tid & 3) << 4) ^ (((tid >> 3) & 3) << 4);

  const int aWOff = wm * 8192;                             // this wave's A half (bytes)
  const int bWOff = (wn >> 1) * 8192 + (wn & 1) * 4096;    // this wave's 64-row B chunk
  const int aRow = tm * 256;
  const int bRow = tn * 256;

  i32x4 acc[8][4];
  #pragma unroll
  for (int i = 0; i < 8; ++i)
    #pragma unroll
    for (int j = 0; j < 4; ++j) acc[i][j] = i32x4{0, 0, 0, 0};

  i32x4 af[4], bq01[2], bq23[2];

  // ---- prologue: K0 -> buf0 (B h0,h1, A h0,h1); K1.B -> buf1; preload g0 ----
  STAGE(B, bRow, 16384, 0, 0);
  STAGE(B, bRow, 16384, 1, 0);
  STAGE(A, aRow, 0,     0, 0);
  STAGE(A, aRow, 0,     1, 0);
  STAGE(B, bRow, 49152, 0, 1);
  STAGE(B, bRow, 49152, 1, 1);
  VM(2);                                        // buf0 K0 fully landed
  SB0();
  BAR();
  LOAD_A(af, 0, 0); LOAD_B2(bq01, 0, 0);        // operands for g0

  #pragma unroll 1
  for (int i = 0; i < 32; ++i) {
    const int kA = 2 * i + 1;                            // <= 63
    const int kB = (2 * i + 2 > 63) ? 63 : 2 * i + 2;    // clamped tail
    const int kC = (2 * i + 3 > 63) ? 63 : 2 * i + 3;
    // g0: MFMA(afL,bq01)@b0; load bq23(b0) for g1; stage buf1.A.h0 <- kA
    PRIO1(); MFMA8(af, 0, bq01, 0); PRIO0(); SB0();
    LOAD_B2(bq23, 0, 2);
    STAGE(A, aRow, 32768, 0, kA);
    BAR();
    // g1: MFMA(afL,bq23); load af<-H(b0) for g2 (WAR-pinned); stage buf1.A.h1
    PRIO1(); MFMA8(af, 0, bq23, 2); PRIO0(); SB0();
    LOAD_A(af, 0, 1);
    STAGE(A, aRow, 32768, 1, kA);
    BAR();
    // g2: MFMA(afH,bq01); no loads; stage buf0.B.h0 <- kB; VM(1) confirms buf1
    PRIO1(); MFMA8(af, 4, bq01, 0); PRIO0(); SB0();
    STAGE(B, bRow, 16384, 0, kB);
    VM(1); SB0();
    BAR();
    // g3: MFMA(afH,bq23); load af<-L(b1) + bq01(b1) for g4; stage buf0.B.h1
    PRIO1(); MFMA8(af, 4, bq23, 2); PRIO0(); SB0();
    LOAD_A(af, 1, 0); LOAD_B2(bq01, 1, 0);
    STAGE(B, bRow, 16384, 1, kB);
    BAR();
    // g4: MFMA(afL,bq01)@b1; load bq23(b1) for g5; stage buf0.A.h0 <- kB
    PRIO1(); MFMA8(af, 0, bq01, 0); PRIO0(); SB0();
    LOAD_B2(bq23, 1, 2);
    STAGE(A, aRow, 0, 0, kB);
    BAR();
    // g5: MFMA(afL,bq23); load af<-H(b1) for g6; stage buf0.A.h1
    PRIO1(); MFMA8(af, 0, bq23, 2); PRIO0(); SB0();
    LOAD_A(af, 1, 1);
    STAGE(A, aRow, 0, 1, kB);
    BAR();
    // g6: MFMA(afH,bq01); no loads; stage buf1.B.h0 <- kC; VM(1) confirms buf0
    PRIO1(); MFMA8(af, 4, bq01, 0); PRIO0(); SB0();
    STAGE(B, bRow, 49152, 0, kC);
    VM(1); SB0();
    BAR();
    // g7: MFMA(afH,bq23); load af<-L(b0') + bq01(b0') for next g0; stage buf1.B.h1
    PRIO1(); MFMA8(af, 4, bq23, 2); PRIO0(); SB0();
    LOAD_A(af, 0, 0); LOAD_B2(bq01, 0, 0);
    STAGE(B, bRow, 49152, 1, kC);
    BAR();
  }

  VM(0);  // drain tail prefetch stages before epilogue

  const float sc = *scale_p;
  float bv[4];
  #pragma unroll
  for (int ni = 0; ni < 4; ++ni) bv[ni] = bias[tn * 256 + wn * 64 + ni * 16 + l15];

  // C/D layout: col = lane&15, row = (lane>>4)*4 + reg (dtype-independent)
  #pragma unroll
  for (int mi = 0; mi < 8; ++mi) {
    #pragma unroll
    for (int r = 0; r < 4; ++r) {
      const int m = tm * 256 + wm * 128 + mi * 16 + (lane >> 4) * 4 + r;
      const float srow_scale = sc * sx[m];
      float* crow = C + (size_t)m * NDIM + tn * 256 + wn * 64;
      #pragma unroll
      for (int ni = 0; ni < 4; ++ni)
        crow[ni * 16 + l15] = srow_scale * (float)acc[mi][ni][r] + bv[ni];
    }
  }
}

extern "C" void kernel_launch(void* const* d_in, const int* in_sizes, int n_in,
                              void* d_out, int out_size, void* d_ws, size_t ws_size,
                              hipStream_t stream) {
  const float* x = (const float*)d_in[0];
  const float* w = (const float*)d_in[1];
  const float* bias = (const float*)d_in[2];
  float* out = (float*)d_out;

  char* ws = (char*)d_ws;
  const size_t XQ_BYTES = (size_t)MDIM * KDIM;   // 33,554,432
  const size_t WQ_BYTES = (size_t)NDIM * KDIM;   // 45,088,768
  char* xq = ws;
  char* wq = ws + XQ_BYTES;
  float* sx = (float*)(ws + XQ_BYTES + WQ_BYTES);
  float* partials = sx + MDIM;
  float* scale = partials + NBLK_W;

  k_convert_w<<<NBLK_W, 256, 0, stream>>>(w, wq, partials);
  k_scale<<<1, 256, 0, stream>>>(partials, scale);
  k_convert_x<<<MDIM, 256, 0, stream>>>(x, xq, sx);

  (void)hipFuncSetAttribute((const void*)k_gemm256,
                            hipFuncAttributeMaxDynamicSharedMemorySize, 65536);
  const int grid = (MDIM / 256) * (NDIM / 256);  // 1376
  k_gemm256<<<grid, 512, 65536, stream>>>(xq, wq, bias, sx, scale, out);
}